// Round 2
// baseline (414.005 us; speedup 1.0000x reference)
//
#include <hip/hip_runtime.h>
#include <cstdint>
#include <cstddef>

#define NSLOPE 0.01f

__device__ __forceinline__ float lrelu(float v) { return v >= 0.f ? v : NSLOPE * v; }

// P[r][c] = bias[c] + sum_k x[r][k] * W[k][c]
// x: [n,100] row-major, W: [100,128] row-major, P: [n,128]
// One thread per column c (block=128), 8 rows per block. x reads are
// wave-uniform (scalar), W reads coalesced and reused across 8 rows.
__global__ __launch_bounds__(128) void node_proj(
    const float* __restrict__ x, const float* __restrict__ W,
    const float* __restrict__ bias, float* __restrict__ P, int n)
{
    const int c  = threadIdx.x;          // 0..127
    const int r0 = blockIdx.x * 8;
    const float bv = bias ? bias[c] : 0.f;

    float acc[8];
    int   rows[8];
#pragma unroll
    for (int i = 0; i < 8; ++i) {
        acc[i] = bv;
        int r = r0 + i;
        rows[i] = (r < n) ? r : (n - 1);
    }

#pragma unroll 4
    for (int k = 0; k < 100; ++k) {
        const float w = W[k * 128 + c];
#pragma unroll
        for (int i = 0; i < 8; ++i)
            acc[i] = fmaf(x[rows[i] * 100 + k], w, acc[i]);
    }

#pragma unroll
    for (int i = 0; i < 8; ++i) {
        int r = r0 + i;
        if (r < n) P[(size_t)r * 128 + c] = acc[i];
    }
}

// Detect whether the edge index buffer is int64 (little-endian, values < 2^31)
// or int32. Only touches the first nwords 32-bit words (= the int32-size of
// the buffer, safe under both interpretations). If int64, all odd words of
// the first half are the zero high-words of row-0 indices.
__global__ void detect_i64(const unsigned int* __restrict__ ew, int nwords, int* flag)
{
    const int t = threadIdx.x;                 // 0..63, one wave
    const long long pairs = nwords / 2;
    const long long step  = pairs / 64;
    unsigned v = 0;
    for (int s = 0; s < 4; ++s) {
        long long p = (long long)t * step + (long long)s * (step / 4 + 1);
        if (p < pairs) v |= ew[2 * p + 1];
    }
    unsigned long long ball = __ballot(v != 0);
    if (t == 0) *flag = (ball == 0ULL) ? 1 : 0;
}

// One thread per edge. Layer 2 streamed (h1 never materialized).
// W2/W3/W4/b* accesses are wave-uniform with compile-time offsets -> s_load.
__global__ __launch_bounds__(256) void edge_mlp(
    const void* __restrict__ eidx_raw,
    const float* __restrict__ Pd, const float* __restrict__ Pi,
    const float* __restrict__ W2, const float* __restrict__ b2,
    const float* __restrict__ W3, const float* __restrict__ b3,
    const float* __restrict__ W4, const float* __restrict__ b4,
    const int* __restrict__ flag64,
    float* __restrict__ out, int E)
{
    const int e = blockIdx.x * blockDim.x + threadIdx.x;
    if (e >= E) return;

    int i0, i1;
    if (*flag64) {
        const long long* p = (const long long*)eidx_raw;
        i0 = (int)p[e];
        i1 = (int)p[(size_t)E + e];
    } else {
        const int* p = (const int*)eidx_raw;
        i0 = p[e];
        i1 = p[(size_t)E + e];
    }

    const float4* pa = (const float4*)(Pd + (size_t)i0 * 128);
    const float4* pb = (const float4*)(Pi + (size_t)i1 * 128);

    float acc2[32];
#pragma unroll
    for (int j = 0; j < 32; ++j) acc2[j] = b2[j];

#pragma unroll 4
    for (int k0 = 0; k0 < 32; ++k0) {
        float4 a = pa[k0];
        float4 b = pb[k0];
        float h0 = lrelu(a.x + b.x);
        float h1 = lrelu(a.y + b.y);
        float h2 = lrelu(a.z + b.z);
        float h3 = lrelu(a.w + b.w);
        const float* w0 = W2 + (k0 * 4 + 0) * 32;
        const float* w1 = W2 + (k0 * 4 + 1) * 32;
        const float* w2 = W2 + (k0 * 4 + 2) * 32;
        const float* w3 = W2 + (k0 * 4 + 3) * 32;
#pragma unroll
        for (int j = 0; j < 32; ++j) {
            float a2 = acc2[j];
            a2 = fmaf(h0, w0[j], a2);
            a2 = fmaf(h1, w1[j], a2);
            a2 = fmaf(h2, w2[j], a2);
            a2 = fmaf(h3, w3[j], a2);
            acc2[j] = a2;
        }
    }

    float acc3[16];
#pragma unroll
    for (int j = 0; j < 16; ++j) acc3[j] = b3[j];
#pragma unroll
    for (int k = 0; k < 32; ++k) {
        float h = lrelu(acc2[k]);
#pragma unroll
        for (int j = 0; j < 16; ++j)
            acc3[j] = fmaf(h, W3[k * 16 + j], acc3[j]);
    }

    float o = b4[0];
#pragma unroll
    for (int k = 0; k < 16; ++k)
        o = fmaf(lrelu(acc3[k]), W4[k], o);

    out[e] = o;
}

extern "C" void kernel_launch(void* const* d_in, const int* in_sizes, int n_in,
                              void* d_out, int out_size, void* d_ws, size_t ws_size,
                              hipStream_t stream)
{
    const float* x_drug = (const float*)d_in[0];
    const float* x_dis  = (const float*)d_in[1];
    const void*  eidx   = d_in[2];
    const float* W1 = (const float*)d_in[3];
    const float* b1 = (const float*)d_in[4];
    const float* W2 = (const float*)d_in[5];
    const float* b2 = (const float*)d_in[6];
    const float* W3 = (const float*)d_in[7];
    const float* b3 = (const float*)d_in[8];
    const float* W4 = (const float*)d_in[9];
    const float* b4 = (const float*)d_in[10];

    const int nd = in_sizes[0] / 100;
    const int ni = in_sizes[1] / 100;
    const int E  = in_sizes[2] / 2;

    float* Pd   = (float*)d_ws;
    float* Pi   = Pd + (size_t)nd * 128;
    int*   flag = (int*)(Pi + (size_t)ni * 128);

    node_proj<<<(nd + 7) / 8, 128, 0, stream>>>(x_drug, W1, nullptr, Pd, nd);
    node_proj<<<(ni + 7) / 8, 128, 0, stream>>>(x_dis, W1 + 100 * 128, b1, Pi, ni);
    detect_i64<<<1, 64, 0, stream>>>((const unsigned int*)eidx, 2 * E, flag);
    edge_mlp<<<(E + 255) / 256, 256, 0, stream>>>(eidx, Pd, Pi,
                                                  W2, b2, W3, b3, W4, b4,
                                                  flag, (float*)d_out, E);
}

// Round 4
// 226.425 us; speedup vs baseline: 1.8284x; 1.8284x over previous
//
#include <hip/hip_runtime.h>
#include <cstdint>
#include <cstddef>

typedef _Float16 hf2 __attribute__((ext_vector_type(2)));

__device__ __forceinline__ hf2 u2h(unsigned u) { union { unsigned u; hf2 h; } c; c.u = u; return c.h; }
__device__ __forceinline__ unsigned h2u(hf2 h) { union { hf2 h; unsigned u; } c; c.h = h; return c.u; }

__device__ __forceinline__ hf2 pkrtz(float lo, float hi) {
    auto v = __builtin_amdgcn_cvt_pkrtz(lo, hi);
    union { decltype(v) a; hf2 b; } c; c.a = v; return c.b;
}

__device__ __forceinline__ float lreluf(float x) { return fmaxf(x, 0.01f * x); }

// add two packed-f16 words, leaky-relu elementwise, return packed word
__device__ __forceinline__ unsigned lr2(unsigned a, unsigned b) {
    hf2 s = u2h(a) + u2h(b);
    hf2 m = s * (_Float16)0.01f;
    hf2 r = __builtin_elementwise_max(s, m);
    return h2u(r);
}

// ---------------------------------------------------------------------------
// node projection: P[r][c] = (bias) + sum_k x[r][k] * W1[koff+k][c], stored f16
// One launch covers both tables. Block 256 = (c 0..127) x (ty 0..1), 16 rows.
__global__ __launch_bounds__(256) void node_proj2(
    const float* __restrict__ xd, const float* __restrict__ xi,
    const float* __restrict__ W1, const float* __restrict__ b1,
    _Float16* __restrict__ Pd, _Float16* __restrict__ Pi,
    int nd, int ni, int nblk_d)
{
    const int c  = threadIdx.x & 127;
    const int ty = threadIdx.x >> 7;
    const bool dis = (int)blockIdx.x >= nblk_d;
    const int b = dis ? (blockIdx.x - nblk_d) : blockIdx.x;
    const int n = dis ? ni : nd;
    const float* x = dis ? xi : xd;
    const float* W = dis ? (W1 + 100 * 128) : W1;
    _Float16* P = dis ? Pi : Pd;
    const float bv = dis ? b1[c] : 0.f;

    const int r0 = b * 16 + ty * 8;
    float acc[8];
    int rows[8];
#pragma unroll
    for (int i = 0; i < 8; ++i) {
        acc[i] = bv;
        int r = r0 + i;
        rows[i] = (r < n) ? r : (n - 1);
    }
#pragma unroll 4
    for (int k = 0; k < 100; ++k) {
        const float w = W[k * 128 + c];
#pragma unroll
        for (int i = 0; i < 8; ++i)
            acc[i] = fmaf(x[rows[i] * 100 + k], w, acc[i]);
    }
#pragma unroll
    for (int i = 0; i < 8; ++i) {
        int r = r0 + i;
        if (r < n) P[(size_t)r * 128 + c] = (_Float16)acc[i];
    }
}

// ---------------------------------------------------------------------------
// pack weights into f16 k-pair layout: Wp[kp][j] = (W[2kp][j], W[2kp+1][j])
__global__ void pack_weights(const float* __restrict__ W2, const float* __restrict__ W3,
                             const float* __restrict__ W4,
                             unsigned* __restrict__ W2p, unsigned* __restrict__ W3p,
                             unsigned* __restrict__ W4p)
{
    const int t = threadIdx.x;
    for (int idx = t; idx < 64 * 32; idx += 256) {
        int kp = idx >> 5, j = idx & 31;
        W2p[idx] = h2u(pkrtz(W2[(2 * kp) * 32 + j], W2[(2 * kp + 1) * 32 + j]));
    }
    for (int idx = t; idx < 16 * 16; idx += 256) {
        int kp = idx >> 4, j = idx & 15;
        W3p[idx] = h2u(pkrtz(W3[(2 * kp) * 16 + j], W3[(2 * kp + 1) * 16 + j]));
    }
    if (t < 8) {
        W4p[t] = h2u(pkrtz(W4[2 * t], W4[2 * t + 1]));
    }
}

// ---------------------------------------------------------------------------
// int64-vs-int32 index format detection (values < 2^31; int64 => odd words 0)
__global__ void detect_i64(const unsigned int* __restrict__ ew, int nwords, int* flag)
{
    const int t = threadIdx.x;
    const long long pairs = nwords / 2;
    const long long step  = pairs / 64;
    unsigned v = 0;
    for (int s = 0; s < 4; ++s) {
        long long p = (long long)t * step + (long long)s * (step / 4 + 1);
        if (p < pairs) v |= ew[2 * p + 1];
    }
    unsigned long long ball = __ballot(v != 0);
    if (t == 0) *flag = (ball == 0ULL) ? 1 : 0;
}

// ---------------------------------------------------------------------------
// Edge MLP. Block = 128 threads, 128 edges. Cooperative coalesced staging of
// h1 = lrelu(Pd[i0] + Pi[i1]) into LDS (f16), then per-thread fdot2 MLP.
__global__ __launch_bounds__(128) void edge_mlp(
    const void* __restrict__ eidx_raw,
    const _Float16* __restrict__ Pd, const _Float16* __restrict__ Pi,
    const unsigned* __restrict__ W2u, const float* __restrict__ b2,
    const unsigned* __restrict__ W3u, const float* __restrict__ b3,
    const unsigned* __restrict__ W4u, const float* __restrict__ b4,
    const int* __restrict__ flag64,
    float* __restrict__ out, int E)
{
    __shared__ uint4 Hs[16][129];   // [chunk][edge], pad 129 -> even superbank spread
    __shared__ int   sidx[2][128];

    const int t   = threadIdx.x;
    const int e_g = blockIdx.x * 128 + t;
    const int e_c = (e_g < E) ? e_g : (E - 1);

    int i0, i1;
    if (*flag64) {
        const long long* p = (const long long*)eidx_raw;
        i0 = (int)p[e_c];
        i1 = (int)p[(size_t)E + e_c];
    } else {
        const int* p = (const int*)eidx_raw;
        i0 = p[e_c];
        i1 = p[(size_t)E + e_c];
    }
    sidx[0][t] = i0;
    sidx[1][t] = i1;
    __syncthreads();

    // ---- stage: 16-lane groups read consecutive 16B chunks of one row ----
    {
        const int c = t & 15;        // chunk within row
        const int r = t >> 4;        // 0..7
        const uint4* Pdq = (const uint4*)Pd;   // 16 uint4 per row
        const uint4* Piq = (const uint4*)Pi;
#pragma unroll
        for (int i = 0; i < 16; ++i) {
            const int e = i * 8 + r;
            const int j0 = sidx[0][e];
            const int j1 = sidx[1][e];
            uint4 A = Pdq[(size_t)j0 * 16 + c];
            uint4 B = Piq[(size_t)j1 * 16 + c];
            uint4 hv;
            hv.x = lr2(A.x, B.x);
            hv.y = lr2(A.y, B.y);
            hv.z = lr2(A.z, B.z);
            hv.w = lr2(A.w, B.w);
            Hs[c][e] = hv;
        }
    }
    __syncthreads();

    // ---- layer 2: 128 -> 32, f16 dot2 with f32 accumulate ----
    float acc[32];
#pragma unroll
    for (int j = 0; j < 32; ++j) acc[j] = b2[j];

#pragma unroll 4
    for (int kc = 0; kc < 16; ++kc) {
        uint4 hq = Hs[kc][t];
        hf2 h0 = u2h(hq.x), h1 = u2h(hq.y), h2 = u2h(hq.z), h3 = u2h(hq.w);
        const unsigned* wb = W2u + kc * 128;   // (4*kc+w)*32 + j
#pragma unroll
        for (int j = 0; j < 32; ++j) acc[j] = __builtin_amdgcn_fdot2(h0, u2h(wb[j]), acc[j], false);
#pragma unroll
        for (int j = 0; j < 32; ++j) acc[j] = __builtin_amdgcn_fdot2(h1, u2h(wb[32 + j]), acc[j], false);
#pragma unroll
        for (int j = 0; j < 32; ++j) acc[j] = __builtin_amdgcn_fdot2(h2, u2h(wb[64 + j]), acc[j], false);
#pragma unroll
        for (int j = 0; j < 32; ++j) acc[j] = __builtin_amdgcn_fdot2(h3, u2h(wb[96 + j]), acc[j], false);
    }

    // ---- layer 3: 32 -> 16 ----
    float a3[16];
#pragma unroll
    for (int j = 0; j < 16; ++j) a3[j] = b3[j];
#pragma unroll
    for (int kp = 0; kp < 16; ++kp) {
        hf2 hp = pkrtz(lreluf(acc[2 * kp]), lreluf(acc[2 * kp + 1]));
#pragma unroll
        for (int j = 0; j < 16; ++j) a3[j] = __builtin_amdgcn_fdot2(hp, u2h(W3u[kp * 16 + j]), a3[j], false);
    }

    // ---- layer 4: 16 -> 1 ----
    float o = b4[0];
#pragma unroll
    for (int kp = 0; kp < 8; ++kp) {
        hf2 hp = pkrtz(lreluf(a3[2 * kp]), lreluf(a3[2 * kp + 1]));
        o = __builtin_amdgcn_fdot2(hp, u2h(W4u[kp]), o, false);
    }

    if (e_g < E) out[e_g] = o;
}

// ---------------------------------------------------------------------------
extern "C" void kernel_launch(void* const* d_in, const int* in_sizes, int n_in,
                              void* d_out, int out_size, void* d_ws, size_t ws_size,
                              hipStream_t stream)
{
    const float* x_drug = (const float*)d_in[0];
    const float* x_dis  = (const float*)d_in[1];
    const void*  eidx   = d_in[2];
    const float* W1 = (const float*)d_in[3];
    const float* b1 = (const float*)d_in[4];
    const float* W2 = (const float*)d_in[5];
    const float* b2 = (const float*)d_in[6];
    const float* W3 = (const float*)d_in[7];
    const float* b3 = (const float*)d_in[8];
    const float* W4 = (const float*)d_in[9];
    const float* b4 = (const float*)d_in[10];

    const int nd = in_sizes[0] / 100;
    const int ni = in_sizes[1] / 100;
    const int E  = in_sizes[2] / 2;

    char* ws = (char*)d_ws;
    _Float16* Pd = (_Float16*)ws;                    size_t off = (size_t)nd * 128 * 2;
    _Float16* Pi = (_Float16*)(ws + off);            off += (size_t)ni * 128 * 2;
    unsigned* W2p = (unsigned*)(ws + off);           off += 64 * 32 * 4;
    unsigned* W3p = (unsigned*)(ws + off);           off += 16 * 16 * 4;
    unsigned* W4p = (unsigned*)(ws + off);           off += 8 * 4;
    int* flag = (int*)(ws + off);

    const int nblk_d = (nd + 15) / 16;
    const int nblk_i = (ni + 15) / 16;

    node_proj2<<<nblk_d + nblk_i, 256, 0, stream>>>(x_drug, x_dis, W1, b1, Pd, Pi, nd, ni, nblk_d);
    pack_weights<<<1, 256, 0, stream>>>(W2, W3, W4, W2p, W3p, W4p);
    detect_i64<<<1, 64, 0, stream>>>((const unsigned int*)eidx, 2 * E, flag);
    edge_mlp<<<(E + 127) / 128, 128, 0, stream>>>(eidx, Pd, Pi,
                                                  W2p, b2, W3p, b3, W4p, b4,
                                                  flag, (float*)d_out, E);
}

// Round 5
// 144.860 us; speedup vs baseline: 2.8580x; 1.5631x over previous
//
#include <hip/hip_runtime.h>
#include <cstdint>
#include <cstddef>

typedef _Float16 hf2   __attribute__((ext_vector_type(2)));
typedef _Float16 f16x8 __attribute__((ext_vector_type(8)));
typedef float    f32x4 __attribute__((ext_vector_type(4)));

__device__ __forceinline__ hf2 u2h(unsigned u) { union { unsigned u; hf2 h; } c; c.u = u; return c.h; }
__device__ __forceinline__ unsigned h2u(hf2 h) { union { hf2 h; unsigned u; } c; c.h = h; return c.u; }
__device__ __forceinline__ f16x8 q2h8(uint4 q) { union { uint4 q; f16x8 h; } c; c.q = q; return c.h; }

__device__ __forceinline__ hf2 pkrtz(float lo, float hi) {
    auto v = __builtin_amdgcn_cvt_pkrtz(lo, hi);
    union { decltype(v) a; hf2 b; } c; c.a = v; return c.b;
}
__device__ __forceinline__ float lreluf(float x) { return fmaxf(x, 0.01f * x); }
// add two packed-f16 words, leaky-relu elementwise
__device__ __forceinline__ unsigned lr2(unsigned a, unsigned b) {
    hf2 s = u2h(a) + u2h(b);
    hf2 m = s * (_Float16)0.01f;
    hf2 r = __builtin_elementwise_max(s, m);
    return h2u(r);
}

// ---------------------------------------------------------------------------
// node projection + (in extra blocks) weight packing + index-format detect.
// P[r][c] = (bias) + sum_k x[r][k] * W1[koff+k][c], stored f16.
// Block 256 = (c 0..127) x (ty 0..1), 16 rows/block; x tile staged in LDS.
__global__ __launch_bounds__(256) void node_proj2(
    const float* __restrict__ xd, const float* __restrict__ xi,
    const float* __restrict__ W1, const float* __restrict__ b1,
    _Float16* __restrict__ Pd, _Float16* __restrict__ Pi,
    int nd, int ni, int nblk_d, int nblk_i,
    const float* __restrict__ W2, const float* __restrict__ W3,
    const float* __restrict__ W4,
    _Float16* __restrict__ W2f, unsigned* __restrict__ W3p,
    unsigned* __restrict__ W4p,
    const unsigned* __restrict__ ew, long long nwords, int* __restrict__ flag)
{
    const int t = threadIdx.x;
    const int nproj = nblk_d + nblk_i;

    if ((int)blockIdx.x >= nproj) {
        // ---- extra block 0: pack weights; extra block 1: detect int64 ----
        if ((int)blockIdx.x == nproj) {
            for (int idx = t; idx < 4096; idx += 256) {
                int i  = idx & 7;
                int l  = (idx >> 3) & 63;
                int kt = (idx >> 9) & 3;
                int nt = (idx >> 11) & 1;
                int k = kt * 32 + 8 * (l >> 4) + i;
                int j = nt * 16 + (l & 15);
                W2f[idx] = (_Float16)W2[k * 32 + j];
            }
            for (int idx = t; idx < 256; idx += 256) {
                int kp = idx >> 4, j = idx & 15;
                W3p[idx] = h2u(pkrtz(W3[(2 * kp) * 16 + j], W3[(2 * kp + 1) * 16 + j]));
            }
            if (t < 8) W4p[t] = h2u(pkrtz(W4[2 * t], W4[2 * t + 1]));
        } else if (t < 64) {
            const long long pairs = nwords / 2;
            const long long step  = pairs / 64;
            unsigned v = 0;
            for (int s = 0; s < 4; ++s) {
                long long p = (long long)t * step + (long long)s * (step / 4 + 1);
                if (p < pairs) v |= ew[2 * p + 1];
            }
            unsigned long long ball = __ballot(v != 0);
            if (t == 0) *flag = (ball == 0ULL) ? 1 : 0;
        }
        return;
    }

    __shared__ float xs[1600];
    const int c  = t & 127;
    const int ty = t >> 7;
    const bool dis = (int)blockIdx.x >= nblk_d;
    const int b = dis ? (blockIdx.x - nblk_d) : blockIdx.x;
    const int n = dis ? ni : nd;
    const float* x = dis ? xi : xd;
    const float* W = dis ? (W1 + 100 * 128) : W1;
    _Float16* P = dis ? Pi : Pd;
    const float bv = dis ? b1[c] : 0.f;
    const int r0 = b * 16;

    const long long gbase = (long long)r0 * 100;
    const long long lim   = (long long)n * 100;
    for (int idx = t; idx < 1600; idx += 256) {
        long long g = gbase + idx;
        xs[idx] = (g < lim) ? x[g] : 0.f;
    }
    __syncthreads();

    float acc[8];
#pragma unroll
    for (int i = 0; i < 8; ++i) acc[i] = bv;

    const float4* xs4 = (const float4*)xs;   // row i base: (ty*8+i)*25 float4
#pragma unroll 5
    for (int kk = 0; kk < 25; ++kk) {
        float w0 = W[(4 * kk + 0) * 128 + c];
        float w1 = W[(4 * kk + 1) * 128 + c];
        float w2 = W[(4 * kk + 2) * 128 + c];
        float w3 = W[(4 * kk + 3) * 128 + c];
#pragma unroll
        for (int i = 0; i < 8; ++i) {
            float4 xv = xs4[(ty * 8 + i) * 25 + kk];
            acc[i] = fmaf(xv.x, w0, acc[i]);
            acc[i] = fmaf(xv.y, w1, acc[i]);
            acc[i] = fmaf(xv.z, w2, acc[i]);
            acc[i] = fmaf(xv.w, w3, acc[i]);
        }
    }
#pragma unroll
    for (int i = 0; i < 8; ++i) {
        int r = r0 + ty * 8 + i;
        if (r < n) P[(size_t)r * 128 + c] = (_Float16)acc[i];
    }
}

// ---------------------------------------------------------------------------
// Edge MLP. Block = 128 threads = 128 edges, 2 waves.
// stage h1 (f16, chunk-XOR-swizzled) -> MFMA layer2 -> LDS bounce -> fdot2 L3/L4.
__global__ __launch_bounds__(128) void edge_mlp(
    const void* __restrict__ eidx_raw,
    const _Float16* __restrict__ Pd, const _Float16* __restrict__ Pi,
    const _Float16* __restrict__ W2f, const float* __restrict__ b2,
    const unsigned* __restrict__ W3u, const float* __restrict__ b3,
    const unsigned* __restrict__ W4u, const float* __restrict__ b4,
    const int* __restrict__ flag64,
    float* __restrict__ out, int E)
{
    __shared__ __align__(16) _Float16 Hs[128 * 128];  // 32 KB; [edge][k], 16B chunks swizzled
    __shared__ int sidx[2][128];
    _Float16* H2 = Hs;                                // overlap: [edge][34] f16, stride 17 dwords

    const int t = threadIdx.x;
    const int l = t & 63;
    const int w = t >> 6;
    const int e_g = blockIdx.x * 128 + t;
    const int e_c = (e_g < E) ? e_g : (E - 1);

    int i0, i1;
    if (*flag64) {
        const long long* p = (const long long*)eidx_raw;
        i0 = (int)p[e_c];
        i1 = (int)p[(size_t)E + e_c];
    } else {
        const int* p = (const int*)eidx_raw;
        i0 = p[e_c];
        i1 = p[(size_t)E + e_c];
    }
    sidx[0][t] = i0;
    sidx[1][t] = i1;

    // B fragments for layer 2 (pre-packed in fragment order; 8 KB, L2-hit)
    f16x8 bf[2][4];
    {
        const uint4* W2q = (const uint4*)W2f;
#pragma unroll
        for (int nt = 0; nt < 2; ++nt)
#pragma unroll
            for (int kt = 0; kt < 4; ++kt)
                bf[nt][kt] = q2h8(W2q[(nt * 4 + kt) * 64 + l]);
    }
    const float b2v0 = b2[l & 15];
    const float b2v1 = b2[16 + (l & 15)];
    __syncthreads();

    // ---- stage h1 = lrelu(Pd[i0]+Pi[i1]) into Hs, 16-lane-coalesced ----
    {
        const int c = t & 15;     // 16B chunk
        const int r = t >> 4;     // 0..7
        const uint4* Pdq = (const uint4*)Pd;
        const uint4* Piq = (const uint4*)Pi;
        uint4* Hq = (uint4*)Hs;
#pragma unroll
        for (int i = 0; i < 16; ++i) {
            const int e = i * 8 + r;
            uint4 A = Pdq[(size_t)sidx[0][e] * 16 + c];
            uint4 B = Piq[(size_t)sidx[1][e] * 16 + c];
            uint4 hv;
            hv.x = lr2(A.x, B.x);
            hv.y = lr2(A.y, B.y);
            hv.z = lr2(A.z, B.z);
            hv.w = lr2(A.w, B.w);
            Hq[e * 16 + (c ^ (e & 7))] = hv;   // m214-style XOR swizzle
        }
    }
    __syncthreads();

    // ---- layer 2 via MFMA 16x16x32 f16: wave w owns mtiles w*4..w*4+3 ----
    f32x4 acc2[4][2];
    {
        const uint4* Hq = (const uint4*)Hs;
        const int er = l & 15;    // A row within tile
        const int cg = l >> 4;    // k chunk-group 0..3
#pragma unroll
        for (int q = 0; q < 4; ++q) {
            const int e = (w * 4 + q) * 16 + er;
#pragma unroll
            for (int nt = 0; nt < 2; ++nt) acc2[q][nt] = (f32x4){0.f, 0.f, 0.f, 0.f};
#pragma unroll
            for (int kt = 0; kt < 4; ++kt) {
                const int c = kt * 4 + cg;
                f16x8 af = q2h8(Hq[e * 16 + (c ^ (e & 7))]);
                acc2[q][0] = __builtin_amdgcn_mfma_f32_16x16x32_f16(af, bf[0][kt], acc2[q][0], 0, 0, 0);
                acc2[q][1] = __builtin_amdgcn_mfma_f32_16x16x32_f16(af, bf[1][kt], acc2[q][1], 0, 0, 0);
            }
        }
    }
    __syncthreads();   // all Hs reads done before H2 overwrite

    // ---- h2 = lrelu(D + b2) -> LDS bounce (f16, stride 34) ----
#pragma unroll
    for (int q = 0; q < 4; ++q) {
#pragma unroll
        for (int nt = 0; nt < 2; ++nt) {
            const float bb = nt ? b2v1 : b2v0;
            const int j = nt * 16 + (l & 15);
#pragma unroll
            for (int r = 0; r < 4; ++r) {
                const int e = (w * 4 + q) * 16 + (l >> 4) * 4 + r;
                H2[e * 34 + j] = (_Float16)lreluf(acc2[q][nt][r] + bb);
            }
        }
    }
    __syncthreads();

    // ---- layers 3,4 per-thread with fdot2 ----
    const unsigned* H2u = (const unsigned*)H2;
    float a3[16];
#pragma unroll
    for (int j = 0; j < 16; ++j) a3[j] = b3[j];
#pragma unroll
    for (int kp = 0; kp < 16; ++kp) {
        hf2 hp = u2h(H2u[t * 17 + kp]);
#pragma unroll
        for (int j = 0; j < 16; ++j)
            a3[j] = __builtin_amdgcn_fdot2(hp, u2h(W3u[kp * 16 + j]), a3[j], false);
    }

    float o = b4[0];
#pragma unroll
    for (int kp = 0; kp < 8; ++kp) {
        hf2 hp = pkrtz(lreluf(a3[2 * kp]), lreluf(a3[2 * kp + 1]));
        o = __builtin_amdgcn_fdot2(hp, u2h(W4u[kp]), o, false);
    }

    if (e_g < E) out[e_g] = o;
}

// ---------------------------------------------------------------------------
extern "C" void kernel_launch(void* const* d_in, const int* in_sizes, int n_in,
                              void* d_out, int out_size, void* d_ws, size_t ws_size,
                              hipStream_t stream)
{
    const float* x_drug = (const float*)d_in[0];
    const float* x_dis  = (const float*)d_in[1];
    const void*  eidx   = d_in[2];
    const float* W1 = (const float*)d_in[3];
    const float* b1 = (const float*)d_in[4];
    const float* W2 = (const float*)d_in[5];
    const float* b2 = (const float*)d_in[6];
    const float* W3 = (const float*)d_in[7];
    const float* b3 = (const float*)d_in[8];
    const float* W4 = (const float*)d_in[9];
    const float* b4 = (const float*)d_in[10];

    const int nd = in_sizes[0] / 100;
    const int ni = in_sizes[1] / 100;
    const int E  = in_sizes[2] / 2;

    char* ws = (char*)d_ws;
    _Float16* Pd = (_Float16*)ws;                    size_t off = (size_t)nd * 128 * 2;
    _Float16* Pi = (_Float16*)(ws + off);            off += (size_t)ni * 128 * 2;
    _Float16* W2f = (_Float16*)(ws + off);           off += 4096 * 2;
    unsigned* W3p = (unsigned*)(ws + off);           off += 16 * 16 * 4;
    unsigned* W4p = (unsigned*)(ws + off);           off += 8 * 4;
    int* flag = (int*)(ws + off);

    const int nblk_d = (nd + 15) / 16;
    const int nblk_i = (ni + 15) / 16;

    node_proj2<<<nblk_d + nblk_i + 2, 256, 0, stream>>>(
        x_drug, x_dis, W1, b1, Pd, Pi, nd, ni, nblk_d, nblk_i,
        W2, W3, W4, W2f, W3p, W4p,
        (const unsigned*)eidx, 2LL * E, flag);

    edge_mlp<<<(E + 127) / 128, 128, 0, stream>>>(eidx, Pd, Pi,
                                                  W2f, b2, W3p, b3, W4p, b4,
                                                  flag, (float*)d_out, E);
}